// Round 2
// baseline (181.546 us; speedup 1.0000x reference)
//
#include <hip/hip_runtime.h>

#define NPG 100     // nodes per graph
#define HF 64       // hidden width
#define SAT 136     // Tc row stride (bf16): 128 + 8 pad (odd multiple of 8 -> b128-friendly)
#define CMW 29      // count-matrix words per row (116 u8 cols; 29 odd -> conflict-free col reads)

typedef float  f4   __attribute__((ext_vector_type(4)));
typedef float  f16v __attribute__((ext_vector_type(16)));
typedef short  bf8  __attribute__((ext_vector_type(8)));

#define NB_T  (HF * SAT * 2)          // 17408 per Tc buffer
#define OFF_MISC (2 * NB_T)           // 34816 (two ping-pong buffers below)
#define MISC_BYTES 2048
#define SMEM_BYTES (OFF_MISC + MISC_BYTES)   // 36864 -> 4 blocks/CU by LDS
// misc layout (bytes from OFF_MISC): dis[112] @0 (448) | b_all[192] @448 (768)
//   | gvn[64] @1216 | zf[32] @1472 | logits[16] @1600 | lsep @1664

// bf16 weight workspace (d_ws), layout Wt[k5][fo][fi]  (= W^T per k):
//   W1t [5][64][16] @ 0  (fi zero-padded 3->16)
//   W2t [5][64][64] @ 5120
//   W3t [5][64][64] @ 25600
#define WT_TOTAL 46080

__device__ __forceinline__ unsigned short f2bf(float f) {
    unsigned u = __float_as_uint(f);
    u += 0x7fffu + ((u >> 16) & 1u);   // round-to-nearest-even
    return (unsigned short)(u >> 16);
}
// HW packed f32->bf16 (RNE), lo -> bits[15:0], hi -> bits[31:16].
__device__ __forceinline__ unsigned cvt_pk_bf16(float lo, float hi) {
    unsigned r;
    asm("v_cvt_pk_bf16_f32 %0, %1, %2" : "=v"(r) : "v"(lo), "v"(hi));
    return r;
}
__device__ __forceinline__ f16v zerov16() {
    f16v z;
    #pragma unroll
    for (int i = 0; i < 16; i++) z[i] = 0.f;
    return z;
}

union BF8U { unsigned u[4]; bf8 b; };

__global__ void wconv(const float* __restrict__ W1, const float* __restrict__ W2,
                      const float* __restrict__ W3, unsigned short* __restrict__ ws)
{
    int idx = blockIdx.x * 256 + threadIdx.x;
    if (idx >= WT_TOTAL) return;
    float v;
    if (idx < 5120) {
        int k5 = idx >> 10, rem = idx & 1023, fo = rem >> 4, fi = rem & 15;
        v = (fi < 3) ? W1[(k5 * 3 + fi) * HF + fo] : 0.f;
    } else if (idx < 25600) {
        int j = idx - 5120;
        int k5 = j >> 12, rem = j & 4095, fo = rem >> 6, fi = rem & 63;
        v = W2[(k5 * HF + fi) * HF + fo];
    } else {
        int j = idx - 25600;
        int k5 = j >> 12, rem = j & 4095, fo = rem >> 6, fi = rem & 63;
        v = W3[(k5 * HF + fi) * HF + fo];
    }
    ws[idx] = f2bf(v);
}

// Transposed-dataflow ChebNet block. One block per graph, 256 threads = 4 waves.
// Wave wg owns node tile np = 32*wg + (lane&31), computes ALL 64 f-columns.
// Everything is T^T [f][node]:
//   LHAT: T_s^T[fo][np] = sum_n T_{s-1}^T[fo][n] * M[np][n]
//     A-frag = Tc rows (b128, LDS, double-buffered), B-frag = M^T in REGISTERS (afT[7]).
//   TW:   out^T[fo][np] += sum_fi Wt[k][fo][fi] * T_s^T[fi][np]
//     A-frag = weights (global, L2-hot), B-frag built from prev[] REGISTERS via
//     v_permlane32_swap_b32 -- zero LDS dependency.
// C/D layout: col(lane&31)=np, row r -> fo = 32ct + (r&3)+8*(r>>2)+4*(lane>>5).
// B-frag element (k=fi=16Ks+8hh+j, col=np) lives in lane (same l31, half j>>2)
// at reg r=(j&3)+8*(Ks&1)+4*hh_dest -> packed word w = 4*(Ks&1)+2*hh_dest+(j>>1 &1...):
// swap(prev[p0+k], prev[p0+2+k]) yields per-lane half0/half1 of word p0+2*hh, k=0,1
// -> exactly dwords {j01, j23, j45, j67}. (Element-checked: Ks=1,l31=5,hh=1,j=6 ->
// fi=30 at reg14/half1/word7 == swap output b1' lo. )
// One barrier per stage (ping-pong Tc). Stage-4 Tc writes are dead -> skipped.
__launch_bounds__(256, 2)
__global__ void chebreg(const float* __restrict__ x, const int* __restrict__ ei,
                        const float* __restrict__ lambda_max,
                        const unsigned short* __restrict__ Wt,
                        const float* __restrict__ b1, const float* __restrict__ b2,
                        const float* __restrict__ b3,
                        const float* __restrict__ bng, const float* __restrict__ bnb,
                        const float* __restrict__ bnm, const float* __restrict__ bnv,
                        const float* __restrict__ fc1w, const float* __restrict__ fc1b,
                        const float* __restrict__ fc2w, const float* __restrict__ fc2b,
                        float* __restrict__ out, int E_total, int epg)
{
    extern __shared__ char sm[];
    const int tid = threadIdx.x;
    const int g = blockIdx.x;
    const int ebase = g * epg, nbase = g * NPG;
    const int wg = tid >> 6, lane = tid & 63;
    const int l31 = lane & 31, hh = lane >> 5;
    const int nb = 32 * wg;
    const int np = nb + l31;
    const bool npv = (np < NPG);

    unsigned* Cm  = (unsigned*)sm;                     // overlays buffer0 (14848 B)
    float* dis    = (float*)(sm + OFF_MISC);           // 112 entries
    float* b_all  = (float*)(sm + OFF_MISC + 448);     // 3 x 64 biases
    float* gvn    = (float*)(sm + OFF_MISC + 1216);
    float* zf     = (float*)(sm + OFF_MISC + 1472);
    float* logits = (float*)(sm + OFF_MISC + 1600);
    float* lsep   = (float*)(sm + OFF_MISC + 1664);

    const float lam = lambda_max[g];
    const float two_l = 2.0f / lam;
    const float cl = two_l - 1.0f;

    // ---------------- u8 count matrix + dis + biases ----------------
    for (int i = tid; i < (128 * CMW) / 4; i += 256)
        ((f4*)Cm)[i] = (f4){0.f, 0.f, 0.f, 0.f};
    __syncthreads();
    for (int e = tid; e < epg; e += 256) {
        int r = ei[ebase + e] - nbase;
        int c = ei[E_total + ebase + e] - nbase;
        atomicAdd(&Cm[r * CMW + (c >> 2)], 1u << (8 * (c & 3)));
    }
    __syncthreads();
    if (tid < 112) {
        float dv = 0.f;
        if (tid < NPG) {
            unsigned s = 0;
            #pragma unroll
            for (int w = 0; w < 25; w++) {   // cols 0..99 live in words 0..24
                unsigned u = Cm[tid * CMW + w];
                s += (u & 255) + ((u >> 8) & 255) + ((u >> 16) & 255) + (u >> 24);
            }
            dv = s > 0 ? rsqrtf((float)s) : 0.f;
        }
        dis[tid] = dv;
    }
    if (tid < 192)
        b_all[tid] = (tid < 64) ? b1[tid] : (tid < 128) ? b2[tid - 64] : b3[tid - 128];
    __syncthreads();

    // ---------------- Ahat^T as B-fragments -> registers (once) ----------------
    // afT[Ks] element (k=n=16Ks+8hh+j, col=np): M[np][n] = -two_l*dis[np]*dis[n]*cnt(np,n) (+cl if n==np)
    bf8 afT[7];
    {
        float base = npv ? (-two_l * dis[np]) : 0.f;
        #pragma unroll
        for (int Ks = 0; Ks < 7; Ks++) {
            int n0 = Ks * 16 + 8 * hh;
            unsigned w0 = npv ? Cm[np * CMW + (n0 >> 2)]     : 0u;
            unsigned w1 = npv ? Cm[np * CMW + (n0 >> 2) + 1] : 0u;
            float vv[8];
            #pragma unroll
            for (int j = 0; j < 8; j++) {
                int n = n0 + j;
                unsigned cnt = (((j < 4) ? w0 : w1) >> (8 * (n & 3))) & 255u;
                float v = base * (float)cnt * dis[n];
                if (npv && n == np) v += cl;
                vv[j] = v;
            }
            BF8U t;
            #pragma unroll
            for (int p = 0; p < 4; p++) t.u[p] = cvt_pk_bf16(vv[2 * p], vv[2 * p + 1]);
            afT[Ks] = t.b;
        }
    }
    __syncthreads();   // Cm reads done before buffer0 (overlay) is zeroed

    // ---------------- zero both Tc buffers, init T0 = x^T ----------------
    for (int i = tid; i < (2 * NB_T) / 16; i += 256)
        ((f4*)sm)[i] = (f4){0.f, 0.f, 0.f, 0.f};
    __syncthreads();

    unsigned prev[2][8], oldr[2][8];
    #pragma unroll
    for (int ct = 0; ct < 2; ct++)
        #pragma unroll
        for (int p = 0; p < 8; p++) prev[ct][p] = 0u;

    if (hh == 0 && npv) {
        float x0 = x[(nbase + np) * 3 + 0];
        float x1 = x[(nbase + np) * 3 + 1];
        float x2 = x[(nbase + np) * 3 + 2];
        prev[0][0] = cvt_pk_bf16(x0, x1);
        prev[0][1] = cvt_pk_bf16(x2, 0.f);
        *(unsigned short*)(sm + (0 * SAT + np) * 2) = (unsigned short)(prev[0][0] & 0xffff);
        *(unsigned short*)(sm + (1 * SAT + np) * 2) = (unsigned short)(prev[0][0] >> 16);
        *(unsigned short*)(sm + (2 * SAT + np) * 2) = (unsigned short)(prev[0][1] & 0xffff);
    }
    __syncthreads();

    // ---------------- 3 ChebConv layers ----------------
    f16v acc[2];
    int cur = 0;

    for (int L = 0; L < 3; L++) {
        const bool l0 = (L == 0);
        const unsigned short* Wl = l0 ? Wt : (Wt + (L == 1 ? 5120 : 25600));
        const int wstr = l0 ? 16 : 64;
        const int nKs  = l0 ? 1 : 4;
        acc[0] = zerov16();
        acc[1] = zerov16();

        // TW from registers: B-frags via permlane32_swap on prev[], A = weights.
        auto TWreg = [&](int k5) {
            #pragma unroll
            for (int Ks = 0; Ks < 4; Ks++) {
                if (Ks < nKs) {
                    unsigned a0 = prev[Ks >> 1][4 * (Ks & 1) + 0];
                    unsigned b0 = prev[Ks >> 1][4 * (Ks & 1) + 2];
                    unsigned a1 = prev[Ks >> 1][4 * (Ks & 1) + 1];
                    unsigned b1v = prev[Ks >> 1][4 * (Ks & 1) + 3];
                    asm volatile("v_permlane32_swap_b32 %0, %1" : "+v"(a0), "+v"(b0));
                    asm volatile("v_permlane32_swap_b32 %0, %1" : "+v"(a1), "+v"(b1v));
                    BF8U bfr; bfr.u[0] = a0; bfr.u[1] = a1; bfr.u[2] = b0; bfr.u[3] = b1v;
                    #pragma unroll
                    for (int ct = 0; ct < 2; ct++) {
                        bf8 wf = *(const bf8*)(Wl + (k5 * 64 + 32 * ct + l31) * wstr
                                               + Ks * 16 + 8 * hh);
                        acc[ct] = __builtin_amdgcn_mfma_f32_32x32x16_bf16(wf, bfr.b, acc[ct], 0, 0, 0);
                    }
                }
            }
        };

        for (int s = 1; s <= 4; s++) {
            const char* bcur = sm + cur * NB_T;
            // A-frags: rows fo of T_{s-1}^T (written before previous barrier)
            bf8 Af0[7], Af1[7];
            #pragma unroll
            for (int Ks = 0; Ks < 7; Ks++)
                Af0[Ks] = *(const bf8*)(bcur + ((0 + l31) * SAT + Ks * 16 + 8 * hh) * 2);
            if (!l0) {
                #pragma unroll
                for (int Ks = 0; Ks < 7; Ks++)
                    Af1[Ks] = *(const bf8*)(bcur + ((32 + l31) * SAT + Ks * 16 + 8 * hh) * 2);
            }
            f16v c0 = zerov16(), c1 = zerov16();
            #pragma unroll
            for (int Ks = 0; Ks < 7; Ks++)
                c0 = __builtin_amdgcn_mfma_f32_32x32x16_bf16(Af0[Ks], afT[Ks], c0, 0, 0, 0);
            if (!l0) {
                #pragma unroll
                for (int Ks = 0; Ks < 7; Ks++)
                    c1 = __builtin_amdgcn_mfma_f32_32x32x16_bf16(Af1[Ks], afT[Ks], c1, 0, 0, 0);
            }

            TWreg(s - 1);   // consumes prev = T_{s-1} BEFORE recurrence update

            // Chebyshev recurrence + pack (registers only)
            #pragma unroll
            for (int p = 0; p < 8; p++) {
                float ve = c0[2 * p], vo = c0[2 * p + 1];
                if (s >= 2) {
                    unsigned o = oldr[0][p];
                    ve = 2.f * ve - __uint_as_float(o << 16);
                    vo = 2.f * vo - __uint_as_float(o & 0xffff0000u);
                }
                oldr[0][p] = prev[0][p];
                prev[0][p] = cvt_pk_bf16(ve, vo);
            }
            if (!l0) {
                #pragma unroll
                for (int p = 0; p < 8; p++) {
                    float ve = c1[2 * p], vo = c1[2 * p + 1];
                    if (s >= 2) {
                        unsigned o = oldr[1][p];
                        ve = 2.f * ve - __uint_as_float(o << 16);
                        vo = 2.f * vo - __uint_as_float(o & 0xffff0000u);
                    }
                    oldr[1][p] = prev[1][p];
                    prev[1][p] = cvt_pk_bf16(ve, vo);
                }
            }

            // write T_s^T -> other buffer (dead at s==4: next consumer is TWreg(4) from regs)
            if (s < 4) {
                char* bnx = sm + (cur ^ 1) * NB_T;
                if (l0) {
                    if (hh == 0) {
                        *(unsigned short*)(bnx + (0 * SAT + np) * 2) = (unsigned short)(prev[0][0] & 0xffff);
                        *(unsigned short*)(bnx + (1 * SAT + np) * 2) = (unsigned short)(prev[0][0] >> 16);
                        *(unsigned short*)(bnx + (2 * SAT + np) * 2) = (unsigned short)(prev[0][1] & 0xffff);
                    }
                } else {
                    #pragma unroll
                    for (int ct = 0; ct < 2; ct++) {
                        #pragma unroll
                        for (int p = 0; p < 8; p++) {
                            int fo = 32 * ct + ((2 * p) & 3) + 8 * (p >> 1) + 4 * hh;
                            *(unsigned short*)(bnx + (fo * SAT + np) * 2)       = (unsigned short)(prev[ct][p] & 0xffff);
                            *(unsigned short*)(bnx + ((fo + 1) * SAT + np) * 2) = (unsigned short)(prev[ct][p] >> 16);
                        }
                    }
                }
            }
            __syncthreads();
            cur ^= 1;
        }

        TWreg(4);

        if (L < 2) {
            // ReLU + bias; result stays in prev[] (= next layer's T0) and goes to Tc[cur]
            const float* bl = b_all + L * 64;
            char* bt0 = sm + cur * NB_T;
            #pragma unroll
            for (int ct = 0; ct < 2; ct++) {
                #pragma unroll
                for (int p = 0; p < 8; p++) {
                    int fo = 32 * ct + ((2 * p) & 3) + 8 * (p >> 1) + 4 * hh;
                    float2 bb = *(const float2*)(bl + fo);   // fo even -> 8B aligned
                    float ve = fmaxf(acc[ct][2 * p]     + bb.x, 0.f);
                    float vo = fmaxf(acc[ct][2 * p + 1] + bb.y, 0.f);
                    prev[ct][p] = cvt_pk_bf16(ve, vo);
                    *(unsigned short*)(bt0 + (fo * SAT + np) * 2)       = (unsigned short)(prev[ct][p] & 0xffff);
                    *(unsigned short*)(bt0 + ((fo + 1) * SAT + np) * 2) = (unsigned short)(prev[ct][p] >> 16);
                }
            }
            __syncthreads();
        } else {
            // mean-pool: f32 scratch [64][132] overlays both Tc buffers (all reads drained
            // by the s=4 barrier). Rows fo, cols np; sum cols 0..99 exactly.
            float* Sc = (float*)sm;
            const float* bl = b_all + 128;
            #pragma unroll
            for (int ct = 0; ct < 2; ct++) {
                #pragma unroll
                for (int p = 0; p < 8; p++) {
                    int fo = 32 * ct + ((2 * p) & 3) + 8 * (p >> 1) + 4 * hh;
                    float2 bb = *(const float2*)(bl + fo);
                    float ve = fmaxf(acc[ct][2 * p]     + bb.x, 0.f);
                    float vo = fmaxf(acc[ct][2 * p + 1] + bb.y, 0.f);
                    if (npv) {
                        Sc[fo * 132 + np]       = ve;
                        Sc[(fo + 1) * 132 + np] = vo;
                    }
                }
            }
            __syncthreads();
            if (tid < HF) {
                float ssum = 0.f;
                #pragma unroll
                for (int k = 0; k < 25; k++) {
                    f4 v = *(const f4*)(Sc + tid * 132 + 4 * k);
                    ssum += v[0] + v[1] + v[2] + v[3];
                }
                float gv = ssum * (1.0f / NPG);
                gv = (gv - bnm[tid]) * rsqrtf(bnv[tid] + 1e-5f) * bng[tid] + bnb[tid];
                gvn[tid] = gv;
            }
            __syncthreads();
        }
    }

    // ---------------- MLP + log_softmax ----------------
    if (tid < 32) {
        float a = fc1b[tid];
        for (int f = 0; f < HF; f++) a += gvn[f] * fc1w[f * 32 + tid];
        zf[tid] = fmaxf(a, 0.f);
    }
    __syncthreads();
    if (tid < 10) {
        float a = fc2b[tid];
        for (int k = 0; k < 32; k++) a += zf[k] * fc2w[k * 10 + tid];
        logits[tid] = a;
    }
    __syncthreads();
    if (tid == 0) {
        float m = logits[0];
        for (int i = 1; i < 10; i++) m = fmaxf(m, logits[i]);
        float s = 0.f;
        for (int i = 0; i < 10; i++) s += expf(logits[i] - m);
        lsep[0] = m + logf(s);
    }
    __syncthreads();
    if (tid < 10) out[g * 10 + tid] = logits[tid] - lsep[0];
}

extern "C" void kernel_launch(void* const* d_in, const int* in_sizes, int n_in,
                              void* d_out, int out_size, void* d_ws, size_t ws_size,
                              hipStream_t stream) {
    const float* x    = (const float*)d_in[0];
    const int*   ei   = (const int*)d_in[1];
    const float* lmax = (const float*)d_in[3];
    const float* W1   = (const float*)d_in[4];
    const float* b1   = (const float*)d_in[5];
    const float* W2   = (const float*)d_in[6];
    const float* b2   = (const float*)d_in[7];
    const float* W3   = (const float*)d_in[8];
    const float* b3   = (const float*)d_in[9];
    const float* bng  = (const float*)d_in[10];
    const float* bnb  = (const float*)d_in[11];
    const float* bnm  = (const float*)d_in[12];
    const float* bnv  = (const float*)d_in[13];
    const float* fc1w = (const float*)d_in[14];
    const float* fc1b = (const float*)d_in[15];
    const float* fc2w = (const float*)d_in[16];
    const float* fc2b = (const float*)d_in[17];

    const int E = in_sizes[1] / 2;
    const int G = in_sizes[3];
    const int epg = E / G;

    unsigned short* Wt = (unsigned short*)d_ws;

    wconv<<<(WT_TOTAL + 255) / 256, 256, 0, stream>>>(W1, W2, W3, Wt);

    hipFuncSetAttribute((const void*)chebreg,
                        hipFuncAttributeMaxDynamicSharedMemorySize, SMEM_BYTES);

    chebreg<<<G, 256, SMEM_BYTES, stream>>>(x, ei, lmax, Wt, b1, b2, b3,
                                            bng, bnb, bnm, bnv, fc1w, fc1b, fc2w, fc2b,
                                            (float*)d_out, E, epg);
}